// Round 1
// baseline (2949.389 us; speedup 1.0000x reference)
//
#include <hip/hip_runtime.h>
#include <math.h>

#define B_ 32
#define N_ 325
#define T_ 12
#define F_ 2
#define C_ 10
#define H_ 64
#define G_ 192   // 3*H
#define BN_ (B_*N_)
#define TOUT_ 12

__device__ __forceinline__ float sigmoid_f(float x) {
    return 1.0f / (1.0f + __expf(-x));
}
__device__ __forceinline__ float tanh_f(float x) {
    float e = __expf(-2.0f * x);
    return (1.0f - e) / (1.0f + e);
}

// One thread per (c, bn) sequence. c = blockIdx.y so all weight addresses are
// wave-uniform -> compiler emits s_load (scalar cache) + v_fma with SGPR
// weight operand. h[64] lives in VGPRs (constant-indexed via unrolled k-loop);
// hn[64] is dynamic-indexed -> scratch (tiny, L1-resident).
__global__ void __launch_bounds__(64) krnn_kernel(
    const float* __restrict__ X,
    const float* __restrict__ eWih, const float* __restrict__ eWhh,
    const float* __restrict__ ebih, const float* __restrict__ ebhh,
    const float* __restrict__ dWih, const float* __restrict__ dWhh,
    const float* __restrict__ dbih, const float* __restrict__ dbhh,
    const float* __restrict__ linW, const float* __restrict__ linb,
    const float* __restrict__ embed, float* __restrict__ out)
{
    const int c  = blockIdx.y;
    const int bn = blockIdx.x * 64 + threadIdx.x;
    if (bn >= BN_) return;
    const int n = bn % N_;

    const float* Xr = X + (size_t)bn * T_ * F_;

    float h[H_];
#pragma unroll
    for (int i = 0; i < H_; ++i) h[i] = 0.0f;
    float hn[H_];

    // ---------------- encoder ----------------
    {
        const float* Wih = eWih + c * G_ * F_;
        const float* Whh = eWhh + (size_t)c * G_ * H_;
        const float* bih = ebih + c * G_;
        const float* bhh = ebhh + c * G_;

        for (int t = 0; t < T_; ++t) {
            float x0 = Xr[t * 2 + 0];
            float x1 = Xr[t * 2 + 1];
            for (int j = 0; j < H_; ++j) {
                const float* wr = Whh + (size_t)j * H_;
                const float* wz = Whh + (size_t)(H_ + j) * H_;
                const float* wn = Whh + (size_t)(2 * H_ + j) * H_;
                float ar = 0.0f, az = 0.0f, an = 0.0f;
#pragma unroll
                for (int k = 0; k < H_; ++k) {
                    ar += h[k] * wr[k];
                    az += h[k] * wz[k];
                    an += h[k] * wn[k];
                }
                float gir = Wih[j * 2] * x0 + Wih[j * 2 + 1] * x1 + bih[j];
                float giz = Wih[(H_ + j) * 2] * x0 + Wih[(H_ + j) * 2 + 1] * x1 + bih[H_ + j];
                float gin = Wih[(2 * H_ + j) * 2] * x0 + Wih[(2 * H_ + j) * 2 + 1] * x1 + bih[2 * H_ + j];
                float r  = sigmoid_f(gir + ar + bhh[j]);
                float z  = sigmoid_f(giz + az + bhh[H_ + j]);
                float nn = tanh_f(gin + r * (an + bhh[2 * H_ + j]));
                hn[j] = (1.0f - z) * nn + z * h[j];
            }
#pragma unroll
            for (int i = 0; i < H_; ++i) h[i] = hn[i];
        }
    }

    // ---------------- softmax mixing weight for this (n, c) ----------------
    float wgt;
    {
        float e[C_];
        float m = -1e30f;
#pragma unroll
        for (int cc = 0; cc < C_; ++cc) {
            e[cc] = embed[n * C_ + cc];
            m = fmaxf(m, e[cc]);
        }
        float den = 0.0f;
#pragma unroll
        for (int cc = 0; cc < C_; ++cc) den += __expf(e[cc] - m);
        wgt = __expf(e[c] - m) / den;
    }

    // ---------------- decoder ----------------
    {
        const float* Wih = dWih + c * G_;           // (G,1) -> G scalars
        const float* Whh = dWhh + (size_t)c * G_ * H_;
        const float* bih = dbih + c * G_;
        const float* bhh = dbhh + c * G_;
        const float* lw  = linW + c * H_;
        const float  lb  = linb[c];

        float lv = Xr[(T_ - 1) * 2 + 0];  // last observed feature 0

        for (int t = 0; t < TOUT_; ++t) {
            for (int j = 0; j < H_; ++j) {
                const float* wr = Whh + (size_t)j * H_;
                const float* wz = Whh + (size_t)(H_ + j) * H_;
                const float* wn = Whh + (size_t)(2 * H_ + j) * H_;
                float ar = 0.0f, az = 0.0f, an = 0.0f;
#pragma unroll
                for (int k = 0; k < H_; ++k) {
                    ar += h[k] * wr[k];
                    az += h[k] * wz[k];
                    an += h[k] * wn[k];
                }
                float gir = Wih[j] * lv + bih[j];
                float giz = Wih[H_ + j] * lv + bih[H_ + j];
                float gin = Wih[2 * H_ + j] * lv + bih[2 * H_ + j];
                float r  = sigmoid_f(gir + ar + bhh[j]);
                float z  = sigmoid_f(giz + az + bhh[H_ + j]);
                float nn = tanh_f(gin + r * (an + bhh[2 * H_ + j]));
                hn[j] = (1.0f - z) * nn + z * h[j];
            }
#pragma unroll
            for (int i = 0; i < H_; ++i) h[i] = hn[i];

            float v = lb;
#pragma unroll
            for (int k = 0; k < H_; ++k) v += lw[k] * h[k];

            atomicAdd(&out[(size_t)bn * TOUT_ + t], wgt * v);
            lv = v;
        }
    }
}

extern "C" void kernel_launch(void* const* d_in, const int* in_sizes, int n_in,
                              void* d_out, int out_size, void* d_ws, size_t ws_size,
                              hipStream_t stream) {
    // setup_inputs order:
    // 0:A 1:X 2:enc_Wih 3:enc_Whh 4:enc_bih 5:enc_bhh
    // 6:dec_Wih 7:dec_Whh 8:dec_bih 9:dec_bhh 10:lin_W 11:lin_b 12:embed
    const float* X    = (const float*)d_in[1];
    const float* eWih = (const float*)d_in[2];
    const float* eWhh = (const float*)d_in[3];
    const float* ebih = (const float*)d_in[4];
    const float* ebhh = (const float*)d_in[5];
    const float* dWih = (const float*)d_in[6];
    const float* dWhh = (const float*)d_in[7];
    const float* dbih = (const float*)d_in[8];
    const float* dbhh = (const float*)d_in[9];
    const float* linW = (const float*)d_in[10];
    const float* linb = (const float*)d_in[11];
    const float* emb  = (const float*)d_in[12];
    float* out = (float*)d_out;

    hipMemsetAsync(d_out, 0, (size_t)out_size * sizeof(float), stream);

    dim3 grid((BN_ + 63) / 64, C_);
    krnn_kernel<<<grid, dim3(64), 0, stream>>>(
        X, eWih, eWhh, ebih, ebhh, dWih, dWhh, dbih, dbhh, linW, linb, emb, out);
}

// Round 2
// 2085.093 us; speedup vs baseline: 1.4145x; 1.4145x over previous
//
#include <hip/hip_runtime.h>
#include <math.h>

#define B_ 32
#define N_ 325
#define T_ 12
#define C_ 10
#define H_ 64
#define G_ 192   // 3*H
#define BN_ (B_*N_)
#define TOUT_ 12

__device__ __forceinline__ float sigmoid_f(float x) {
    return 1.0f / (1.0f + __expf(-x));
}
__device__ __forceinline__ float tanh_f(float x) {
    float e = __expf(-2.0f * x);
    return (1.0f - e) / (1.0f + e);
}

// lane = sequence (bn), c = blockIdx.y  (weights wave-uniform -> s_load +
// v_fmac with SGPR operand). h[64] lives in VGPRs, constant-indexed in the
// fully-unrolled k loop. The dynamic-j write of h_new goes to LDS
// hbuf[j][lane] (conflict-free: consecutive lanes -> consecutive banks);
// next step reads it back into registers. Single wave per block -> same-wave
// LDS ordering, no barriers. Old h[j] at dynamic j is read from the
// not-yet-overwritten LDS slot.
__global__ void __launch_bounds__(64, 4) krnn_kernel(
    const float* __restrict__ X,
    const float* __restrict__ eWih, const float* __restrict__ eWhh,
    const float* __restrict__ ebih, const float* __restrict__ ebhh,
    const float* __restrict__ dWih, const float* __restrict__ dWhh,
    const float* __restrict__ dbih, const float* __restrict__ dbhh,
    const float* __restrict__ linW, const float* __restrict__ linb,
    const float* __restrict__ embed, float* __restrict__ out)
{
    __shared__ float hbuf[H_ * 64];   // [j][lane], 16 KB

    const int c    = blockIdx.y;
    const int lane = threadIdx.x;
    int bn = blockIdx.x * 64 + lane;
    const bool active = (bn < BN_);
    if (!active) bn = BN_ - 1;        // clamp: duplicate compute, masked store
    const int n = bn % N_;

    const float* __restrict__ Xr = X + (size_t)bn * (T_ * 2);

    // h lives in VGPRs; hbuf holds the same values for dynamic-index access
    float h[H_];
#pragma unroll
    for (int i = 0; i < H_; ++i) h[i] = 0.0f;
#pragma unroll
    for (int i = 0; i < H_; ++i) hbuf[i * 64 + lane] = 0.0f;

    // ---------------- encoder ----------------
    {
        const float* __restrict__ Wih = eWih + c * (G_ * 2);
        const float* __restrict__ Whh = eWhh + (size_t)c * (G_ * H_);
        const float* __restrict__ bih = ebih + c * G_;
        const float* __restrict__ bhh = ebhh + c * G_;

        for (int t = 0; t < T_; ++t) {
            const float x0 = Xr[2 * t];
            const float x1 = Xr[2 * t + 1];
            for (int j = 0; j < H_; ++j) {
                const float* __restrict__ wr = Whh + j * H_;
                const float* __restrict__ wz = wr + H_ * H_;
                const float* __restrict__ wn = wz + H_ * H_;
                float ar = 0.0f, az = 0.0f, an = 0.0f;
#pragma unroll
                for (int k = 0; k < H_; ++k) {
                    ar = fmaf(h[k], wr[k], ar);
                    az = fmaf(h[k], wz[k], az);
                    an = fmaf(h[k], wn[k], an);
                }
                const float gir = fmaf(Wih[2*j],         x0, fmaf(Wih[2*j+1],         x1, bih[j]));
                const float giz = fmaf(Wih[2*(H_+j)],    x0, fmaf(Wih[2*(H_+j)+1],    x1, bih[H_+j]));
                const float gin = fmaf(Wih[2*(2*H_+j)],  x0, fmaf(Wih[2*(2*H_+j)+1],  x1, bih[2*H_+j]));
                const float r  = sigmoid_f(gir + ar + bhh[j]);
                const float z  = sigmoid_f(giz + az + bhh[H_ + j]);
                const float nn = tanh_f(gin + r * (an + bhh[2 * H_ + j]));
                const float hold = hbuf[j * 64 + lane];      // old h[j] (not yet overwritten)
                hbuf[j * 64 + lane] = (1.0f - z) * nn + z * hold;
            }
            // pull new h back into registers (constant-indexed)
#pragma unroll
            for (int k = 0; k < H_; ++k) h[k] = hbuf[k * 64 + lane];
        }
    }

    // ---------------- softmax mixing weight for this (n, c) ----------------
    float wgt;
    {
        float e[C_];
        float m = -1e30f;
#pragma unroll
        for (int cc = 0; cc < C_; ++cc) {
            e[cc] = embed[n * C_ + cc];
            m = fmaxf(m, e[cc]);
        }
        float den = 0.0f;
#pragma unroll
        for (int cc = 0; cc < C_; ++cc) den += __expf(e[cc] - m);
        wgt = __expf(e[c] - m) / den;
    }

    // ---------------- decoder ----------------
    {
        const float* __restrict__ Wih = dWih + c * G_;   // (G,1) -> G scalars
        const float* __restrict__ Whh = dWhh + (size_t)c * (G_ * H_);
        const float* __restrict__ bih = dbih + c * G_;
        const float* __restrict__ bhh = dbhh + c * G_;
        const float* __restrict__ lw  = linW + c * H_;
        const float  lb = linb[c];

        float lv = Xr[(T_ - 1) * 2 + 0];   // last observed feature 0

        for (int t = 0; t < TOUT_; ++t) {
            for (int j = 0; j < H_; ++j) {
                const float* __restrict__ wr = Whh + j * H_;
                const float* __restrict__ wz = wr + H_ * H_;
                const float* __restrict__ wn = wz + H_ * H_;
                float ar = 0.0f, az = 0.0f, an = 0.0f;
#pragma unroll
                for (int k = 0; k < H_; ++k) {
                    ar = fmaf(h[k], wr[k], ar);
                    az = fmaf(h[k], wz[k], az);
                    an = fmaf(h[k], wn[k], an);
                }
                const float gir = fmaf(Wih[j],          lv, bih[j]);
                const float giz = fmaf(Wih[H_ + j],     lv, bih[H_ + j]);
                const float gin = fmaf(Wih[2 * H_ + j], lv, bih[2 * H_ + j]);
                const float r  = sigmoid_f(gir + ar + bhh[j]);
                const float z  = sigmoid_f(giz + az + bhh[H_ + j]);
                const float nn = tanh_f(gin + r * (an + bhh[2 * H_ + j]));
                const float hold = hbuf[j * 64 + lane];
                hbuf[j * 64 + lane] = (1.0f - z) * nn + z * hold;
            }
#pragma unroll
            for (int k = 0; k < H_; ++k) h[k] = hbuf[k * 64 + lane];

            float v = lb;
#pragma unroll
            for (int k = 0; k < H_; ++k) v = fmaf(lw[k], h[k], v);

            if (active) atomicAdd(&out[(size_t)bn * TOUT_ + t], wgt * v);
            lv = v;
        }
    }
}

extern "C" void kernel_launch(void* const* d_in, const int* in_sizes, int n_in,
                              void* d_out, int out_size, void* d_ws, size_t ws_size,
                              hipStream_t stream) {
    // setup_inputs order:
    // 0:A 1:X 2:enc_Wih 3:enc_Whh 4:enc_bih 5:enc_bhh
    // 6:dec_Wih 7:dec_Whh 8:dec_bih 9:dec_bhh 10:lin_W 11:lin_b 12:embed
    const float* X    = (const float*)d_in[1];
    const float* eWih = (const float*)d_in[2];
    const float* eWhh = (const float*)d_in[3];
    const float* ebih = (const float*)d_in[4];
    const float* ebhh = (const float*)d_in[5];
    const float* dWih = (const float*)d_in[6];
    const float* dWhh = (const float*)d_in[7];
    const float* dbih = (const float*)d_in[8];
    const float* dbhh = (const float*)d_in[9];
    const float* linW = (const float*)d_in[10];
    const float* linb = (const float*)d_in[11];
    const float* emb  = (const float*)d_in[12];
    float* out = (float*)d_out;

    hipMemsetAsync(d_out, 0, (size_t)out_size * sizeof(float), stream);

    dim3 grid((BN_ + 63) / 64, C_);
    krnn_kernel<<<grid, dim3(64), 0, stream>>>(
        X, eWih, eWhh, ebih, ebhh, dWih, dWhh, dbih, dbhh, linW, linb, emb, out);
}

// Round 3
// 589.966 us; speedup vs baseline: 4.9993x; 3.5343x over previous
//
#include <hip/hip_runtime.h>
#include <math.h>

#define B_ 32
#define N_ 325
#define BN_ (B_*N_)

// MFMA fragment types per guide §3 (compile-verified on gfx950)
typedef short s8v __attribute__((ext_vector_type(8)));   // 8 bf16 in 4 VGPRs
typedef float f4v __attribute__((ext_vector_type(4)));   // 4 fp32 acc

__device__ __forceinline__ short f2bf(float x){          // fp32 -> bf16 RNE
    unsigned u = __float_as_uint(x);
    u += 0x7fffu + ((u >> 16) & 1u);
    return (short)(u >> 16);
}
__device__ __forceinline__ float bf2f(short h){
    return __uint_as_float(((unsigned)(unsigned short)h) << 16);
}
__device__ __forceinline__ float sigm(float x){ return 1.0f/(1.0f+__expf(-x)); }
__device__ __forceinline__ float tanh_f(float x){
    float e = __expf(-2.0f * x);
    return (1.0f - e) / (1.0f + e);
}

// Swizzled plane index: element (m,k) of a [rows][64] bf16 plane.
// 16B blocks (8 shorts) XOR-swizzled by row -> ds_read_b128 of a fragment
// (8 consecutive k for fixed m) is 16B-aligned and ~conflict-free.
__device__ __forceinline__ int plane_idx(int m, int k){
    return m * 64 + ((((k >> 3) ^ (m & 7)) << 3) | (k & 7));
}
__device__ __forceinline__ int frag_idx(int m, int kb){  // kb = k/8
    return m * 64 + ((kb ^ (m & 7)) << 3);
}

// Block: 256 threads = 4 waves, 64 sequences (rows), one cluster c.
// Wave w owns j-columns [16w,16w+16): computes gh tiles for gates r,z,n at
// N-cols {j, j+64, j+128} via mfma_f32_16x16x32_bf16, split-bf16 3-pass
// (Ahi*Bhi + Alo*Bhi + Ahi*Blo). Gating is lane-local (C/D layout row=kg*4+reg,
// col=nl identical across the 3 gate tiles). h round-trips LDS planes
// (C/D layout -> A layout transpose). 2 barriers/step.
__global__ void __launch_bounds__(256, 2) krnn_kernel(
    const float* __restrict__ X,
    const float* __restrict__ eWih, const float* __restrict__ eWhh,
    const float* __restrict__ ebih, const float* __restrict__ ebhh,
    const float* __restrict__ dWih, const float* __restrict__ dWhh,
    const float* __restrict__ dbih, const float* __restrict__ dbhh,
    const float* __restrict__ linW, const float* __restrict__ linb,
    const float* __restrict__ embed, float* __restrict__ out)
{
    __shared__ short sBhi[192 * 64], sBlo[192 * 64];   // Whh bf16 hi/lo planes (48 KB)
    __shared__ short sHhi[64 * 64],  sHlo[64 * 64];    // h bf16 hi/lo planes (16 KB)
    __shared__ float sX[64 * 24];                      // staged X rows (6 KB)
    __shared__ float sWih[384], sBih[192], sBhh[192];  // encoder smalls
    __shared__ float sDWih[192], sDBih[192], sDBhh[192];
    __shared__ float sLw[64], sWgt[64], sLv[64], sVp[256];
    __shared__ float sLb[1];

    const int c    = blockIdx.y;
    const int row0 = blockIdx.x * 64;
    const int tid  = threadIdx.x;
    const int lane = tid & 63;
    const int wv   = tid >> 6;        // wave id = j-tile
    const int nl   = lane & 15;       // frag col / A-row lane index
    const int kg   = lane >> 4;       // k-group / C/D row-group
    const int jcol = wv * 16 + nl;    // this lane's h-column (gating + B col)

    // ---------------- prologue: stage everything ----------------
    for (int i = tid; i < 64 * 24; i += 256) {
        int m = i / 24, q = i - m * 24;
        int bn = row0 + m; if (bn >= BN_) bn = BN_ - 1;
        sX[i] = X[bn * 24 + q];
    }
    for (int i = tid; i < 192; i += 256) {
        sWih[2*i]   = eWih[c * 384 + 2*i];
        sWih[2*i+1] = eWih[c * 384 + 2*i + 1];
        sBih[i]  = ebih[c * 192 + i];
        sBhh[i]  = ebhh[c * 192 + i];
        sDWih[i] = dWih[c * 192 + i];
        sDBih[i] = dbih[c * 192 + i];
        sDBhh[i] = dbhh[c * 192 + i];
    }
    if (tid < 64) sLw[tid] = linW[c * 64 + tid];
    if (tid == 0) sLb[0] = linb[c];
    if (tid < 64) {   // softmax mixing weight per row
        int bn = row0 + tid; if (bn >= BN_) bn = BN_ - 1;
        int n = bn % N_;
        float e[10], mx = -1e30f;
#pragma unroll
        for (int cc = 0; cc < 10; ++cc) { e[cc] = embed[n * 10 + cc]; mx = fmaxf(mx, e[cc]); }
        float den = 0.0f;
#pragma unroll
        for (int cc = 0; cc < 10; ++cc) den += __expf(e[cc] - mx);
        sWgt[tid] = __expf(e[c] - mx) / den;
    }
    // encoder Whh -> split bf16 planes (B-frag layout: row g, cols k)
    for (int i = tid; i < 192 * 64; i += 256) {
        int g = i >> 6, k = i & 63;
        float w = eWhh[c * 12288 + i];
        short hi = f2bf(w); short lo = f2bf(w - bf2f(hi));
        int idx = plane_idx(g, k);
        sBhi[idx] = hi; sBlo[idx] = lo;
    }
    for (int i = tid; i < 64 * 64; i += 256) { sHhi[i] = 0; sHlo[i] = 0; }

    float hreg[4][4];   // h_old in C/D layout: [Mt][reg], row=Mt*16+kg*4+reg, col=jcol
#pragma unroll
    for (int a = 0; a < 4; ++a)
#pragma unroll
        for (int b = 0; b < 4; ++b) hreg[a][b] = 0.0f;

    __syncthreads();

    // hoisted encoder gate coefficients for this lane's column
    float ew0[3], ew1[3], ebi[3], ebh[3];
#pragma unroll
    for (int g3 = 0; g3 < 3; ++g3) {
        int gc = g3 * 64 + jcol;
        ew0[g3] = sWih[2*gc]; ew1[g3] = sWih[2*gc+1];
        ebi[g3] = sBih[gc];   ebh[g3] = sBhh[gc];
    }

    // ---------------- encoder: 12 steps ----------------
    for (int t = 0; t < 12; ++t) {
        // A fragments (old h), rows Mt*16+nl, k contiguous
        s8v Ahi[4][2], Alo[4][2];
#pragma unroll
        for (int Mt = 0; Mt < 4; ++Mt) {
            int m = Mt * 16 + nl;
#pragma unroll
            for (int ch = 0; ch < 2; ++ch) {
                int idx = frag_idx(m, ch * 4 + kg);
                Ahi[Mt][ch] = *(const s8v*)&sHhi[idx];
                Alo[Mt][ch] = *(const s8v*)&sHlo[idx];
            }
        }
        __syncthreads();   // all A-reads done before anyone overwrites h

        f4v acc[4][3];
#pragma unroll
        for (int Mt = 0; Mt < 4; ++Mt)
#pragma unroll
            for (int g3 = 0; g3 < 3; ++g3)
#pragma unroll
                for (int r4 = 0; r4 < 4; ++r4) acc[Mt][g3][r4] = 0.0f;

#pragma unroll
        for (int g3 = 0; g3 < 3; ++g3) {
            int gcol = g3 * 64 + jcol;
#pragma unroll
            for (int ch = 0; ch < 2; ++ch) {
                int idx = frag_idx(gcol, ch * 4 + kg);
                s8v Bh = *(const s8v*)&sBhi[idx];
                s8v Bl = *(const s8v*)&sBlo[idx];
#pragma unroll
                for (int Mt = 0; Mt < 4; ++Mt) {
                    acc[Mt][g3] = __builtin_amdgcn_mfma_f32_16x16x32_bf16(Ahi[Mt][ch], Bh, acc[Mt][g3], 0, 0, 0);
                    acc[Mt][g3] = __builtin_amdgcn_mfma_f32_16x16x32_bf16(Alo[Mt][ch], Bh, acc[Mt][g3], 0, 0, 0);
                    acc[Mt][g3] = __builtin_amdgcn_mfma_f32_16x16x32_bf16(Ahi[Mt][ch], Bl, acc[Mt][g3], 0, 0, 0);
                }
            }
        }

        // gating (lane-local) + write new h planes
#pragma unroll
        for (int Mt = 0; Mt < 4; ++Mt) {
#pragma unroll
            for (int r4 = 0; r4 < 4; ++r4) {
                int m = Mt * 16 + kg * 4 + r4;
                float x0 = sX[m * 24 + 2 * t], x1 = sX[m * 24 + 2 * t + 1];
                float r  = sigm(acc[Mt][0][r4] + ew0[0]*x0 + ew1[0]*x1 + ebi[0] + ebh[0]);
                float z  = sigm(acc[Mt][1][r4] + ew0[1]*x0 + ew1[1]*x1 + ebi[1] + ebh[1]);
                float nn = tanh_f(ew0[2]*x0 + ew1[2]*x1 + ebi[2] + r * (acc[Mt][2][r4] + ebh[2]));
                float hnew = nn + z * (hreg[Mt][r4] - nn);
                hreg[Mt][r4] = hnew;
                short hi = f2bf(hnew); short lo = f2bf(hnew - bf2f(hi));
                int idx = plane_idx(m, jcol);
                sHhi[idx] = hi; sHlo[idx] = lo;
            }
        }
        __syncthreads();   // h planes complete for next step
    }

    // ---------------- swap weights to decoder, init lv ----------------
    for (int i = tid; i < 192 * 64; i += 256) {
        int g = i >> 6, k = i & 63;
        float w = dWhh[c * 12288 + i];
        short hi = f2bf(w); short lo = f2bf(w - bf2f(hi));
        int idx = plane_idx(g, k);
        sBhi[idx] = hi; sBlo[idx] = lo;
    }
    if (tid < 64) sLv[tid] = sX[tid * 24 + 22];   // last observed feature 0
    __syncthreads();

    float dw[3], dbi[3], dbh[3];
#pragma unroll
    for (int g3 = 0; g3 < 3; ++g3) {
        int gc = g3 * 64 + jcol;
        dw[g3] = sDWih[gc]; dbi[g3] = sDBih[gc]; dbh[g3] = sDBhh[gc];
    }
    const float lwl = sLw[jcol];
    const float lb  = sLb[0];

    // ---------------- decoder: 12 steps ----------------
    for (int t = 0; t < 12; ++t) {
        s8v Ahi[4][2], Alo[4][2];
#pragma unroll
        for (int Mt = 0; Mt < 4; ++Mt) {
            int m = Mt * 16 + nl;
#pragma unroll
            for (int ch = 0; ch < 2; ++ch) {
                int idx = frag_idx(m, ch * 4 + kg);
                Ahi[Mt][ch] = *(const s8v*)&sHhi[idx];
                Alo[Mt][ch] = *(const s8v*)&sHlo[idx];
            }
        }
        __syncthreads();

        f4v acc[4][3];
#pragma unroll
        for (int Mt = 0; Mt < 4; ++Mt)
#pragma unroll
            for (int g3 = 0; g3 < 3; ++g3)
#pragma unroll
                for (int r4 = 0; r4 < 4; ++r4) acc[Mt][g3][r4] = 0.0f;

#pragma unroll
        for (int g3 = 0; g3 < 3; ++g3) {
            int gcol = g3 * 64 + jcol;
#pragma unroll
            for (int ch = 0; ch < 2; ++ch) {
                int idx = frag_idx(gcol, ch * 4 + kg);
                s8v Bh = *(const s8v*)&sBhi[idx];
                s8v Bl = *(const s8v*)&sBlo[idx];
#pragma unroll
                for (int Mt = 0; Mt < 4; ++Mt) {
                    acc[Mt][g3] = __builtin_amdgcn_mfma_f32_16x16x32_bf16(Ahi[Mt][ch], Bh, acc[Mt][g3], 0, 0, 0);
                    acc[Mt][g3] = __builtin_amdgcn_mfma_f32_16x16x32_bf16(Alo[Mt][ch], Bh, acc[Mt][g3], 0, 0, 0);
                    acc[Mt][g3] = __builtin_amdgcn_mfma_f32_16x16x32_bf16(Ahi[Mt][ch], Bl, acc[Mt][g3], 0, 0, 0);
                }
            }
        }

#pragma unroll
        for (int Mt = 0; Mt < 4; ++Mt) {
#pragma unroll
            for (int r4 = 0; r4 < 4; ++r4) {
                int m = Mt * 16 + kg * 4 + r4;
                float lv = sLv[m];
                float r  = sigm(acc[Mt][0][r4] + dw[0]*lv + dbi[0] + dbh[0]);
                float z  = sigm(acc[Mt][1][r4] + dw[1]*lv + dbi[1] + dbh[1]);
                float nn = tanh_f(dw[2]*lv + dbi[2] + r * (acc[Mt][2][r4] + dbh[2]));
                float hnew = nn + z * (hreg[Mt][r4] - nn);
                hreg[Mt][r4] = hnew;
                short hi = f2bf(hnew); short lo = f2bf(hnew - bf2f(hi));
                int idx = plane_idx(m, jcol);
                sHhi[idx] = hi; sHlo[idx] = lo;

                // partial of v[m] over this wave's 16 columns
                float p = lwl * hnew;
                p += __shfl_xor(p, 1, 16);
                p += __shfl_xor(p, 2, 16);
                p += __shfl_xor(p, 4, 16);
                p += __shfl_xor(p, 8, 16);
                if (nl == 0) sVp[wv * 64 + m] = p;
            }
        }
        __syncthreads();   // h planes + v partials complete

        if (tid < 64) {
            float v = sVp[tid] + sVp[64 + tid] + sVp[128 + tid] + sVp[192 + tid] + lb;
            sLv[tid] = v;
            int bn = row0 + tid;
            if (bn < BN_) atomicAdd(&out[(size_t)bn * 12 + t], sWgt[tid] * v);
        }
        // next iteration's post-A-read barrier orders sLv for all waves
    }
}

extern "C" void kernel_launch(void* const* d_in, const int* in_sizes, int n_in,
                              void* d_out, int out_size, void* d_ws, size_t ws_size,
                              hipStream_t stream) {
    // 0:A 1:X 2:enc_Wih 3:enc_Whh 4:enc_bih 5:enc_bhh
    // 6:dec_Wih 7:dec_Whh 8:dec_bih 9:dec_bhh 10:lin_W 11:lin_b 12:embed
    const float* X    = (const float*)d_in[1];
    const float* eWih = (const float*)d_in[2];
    const float* eWhh = (const float*)d_in[3];
    const float* ebih = (const float*)d_in[4];
    const float* ebhh = (const float*)d_in[5];
    const float* dWih = (const float*)d_in[6];
    const float* dWhh = (const float*)d_in[7];
    const float* dbih = (const float*)d_in[8];
    const float* dbhh = (const float*)d_in[9];
    const float* linW = (const float*)d_in[10];
    const float* linb = (const float*)d_in[11];
    const float* emb  = (const float*)d_in[12];
    float* out = (float*)d_out;

    hipMemsetAsync(d_out, 0, (size_t)out_size * sizeof(float), stream);

    dim3 grid((BN_ + 63) / 64, 10);
    krnn_kernel<<<grid, dim3(256), 0, stream>>>(
        X, eWih, eWhh, ebih, ebhh, dWih, dWhh, dbih, dbhh, linW, linb, emb, out);
}

// Round 4
// 427.449 us; speedup vs baseline: 6.9000x; 1.3802x over previous
//
#include <hip/hip_runtime.h>
#include <math.h>

#define N_   325
#define BN_  10400
#define R_   16            // rows (sequences) per block; 10400/16 = 650 exact

typedef short s8v __attribute__((ext_vector_type(8)));   // 8 bf16 (4 VGPRs)
typedef float f4v __attribute__((ext_vector_type(4)));   // 4 fp32 acc

__device__ __forceinline__ float bf2f_hi(unsigned u){    // value of truncated-hi part
    return __uint_as_float(u & 0xffff0000u);
}
__device__ __forceinline__ short f2bf_rne(float x){
    unsigned u = __float_as_uint(x);
    u += 0x7fffu + ((u >> 16) & 1u);
    return (short)(u >> 16);
}
__device__ __forceinline__ float sigm(float x){ return 1.0f/(1.0f+__expf(-x)); }
__device__ __forceinline__ float tanh_f(float x){
    float e = __expf(-2.0f*x); return (1.0f-e)/(1.0f+e);
}
// h-plane [R_][64] bf16, 16B blocks XOR-swizzled by row -> b128 frag reads
// are 16B-aligned and ~conflict-free (2-way max = free).
__device__ __forceinline__ int plane_idx(int m,int k){
    return m*64 + ((((k>>3)^(m&7))<<3)|(k&7));
}
__device__ __forceinline__ int frag_idx(int m,int kb){   // kb = k/8
    return m*64 + ((kb^(m&7))<<3);
}

// Block: 256 thr = 4 waves, 16 rows, one cluster c. Wave w owns j-cols
// [16w,16w+16). B (Whh) fragments live in 48 VGPRs per lane, loaded from
// global once per phase (no LDS, no staging prologue). h round-trips 4 KB
// LDS planes (split bf16: truncated hi + RNE lo -> exact correction).
// gh = h*Whh^T via mfma_f32_16x16x32_bf16, 3-pass split (AhiBhi+AloBhi+AhiBlo).
__global__ void __launch_bounds__(256, 4) krnn_kernel(
    const float* __restrict__ X,
    const float* __restrict__ eWih, const float* __restrict__ eWhh,
    const float* __restrict__ ebih, const float* __restrict__ ebhh,
    const float* __restrict__ dWih, const float* __restrict__ dWhh,
    const float* __restrict__ dbih, const float* __restrict__ dbhh,
    const float* __restrict__ linW, const float* __restrict__ linb,
    const float* __restrict__ embed, float* __restrict__ out)
{
    __shared__ short sHhi[R_*64], sHlo[R_*64];   // 2 KB + 2 KB
    __shared__ float sX[R_*24];                  // 1.5 KB
    __shared__ float sWgt[R_], sLv[R_], sVp[4*R_];

    const int c    = blockIdx.y;
    const int row0 = blockIdx.x * R_;
    const int tid  = threadIdx.x;
    const int lane = tid & 63;
    const int wv   = tid >> 6;
    const int nl   = lane & 15;
    const int kg   = lane >> 4;
    const int jcol = wv*16 + nl;      // this lane's h-column

    // ---------------- prologue ----------------
    for (int i = tid; i < R_*24; i += 256) {
        int m = i / 24, q = i - m*24;
        sX[i] = X[(row0 + m)*24 + q];
    }
    if (tid < R_) {                   // softmax mixing weight per row
        int n = (row0 + tid) % N_;
        float e[10], mx = -1e30f;
#pragma unroll
        for (int cc = 0; cc < 10; ++cc){ e[cc] = embed[n*10+cc]; mx = fmaxf(mx, e[cc]); }
        float den = 0.0f;
#pragma unroll
        for (int cc = 0; cc < 10; ++cc) den += __expf(e[cc]-mx);
        sWgt[tid] = __expf(e[c]-mx) / den;
    }

    // B fragments (encoder Whh) -> registers, split bf16
    s8v Bh[3][2], Bl[3][2];
    {
        const float* __restrict__ Whh = eWhh + c*12288;
#pragma unroll
        for (int g3 = 0; g3 < 3; ++g3)
#pragma unroll
            for (int ch = 0; ch < 2; ++ch) {
                const float* p = Whh + (g3*64 + jcol)*64 + ch*32 + kg*8;
                float4 a = *(const float4*)p;
                float4 b = *(const float4*)(p + 4);
                float w[8] = {a.x,a.y,a.z,a.w,b.x,b.y,b.z,b.w};
                s8v bh, bl;
#pragma unroll
                for (int i = 0; i < 8; ++i) {
                    unsigned u = __float_as_uint(w[i]);
                    bh[i] = (short)(u >> 16);
                    bl[i] = f2bf_rne(w[i] - bf2f_hi(u));
                }
                Bh[g3][ch] = bh; Bl[g3][ch] = bl;
            }
    }

    // encoder gate constants for this lane's column
    float ew0[3], ew1[3], ebs[3], ebi_n, ebh_n;
#pragma unroll
    for (int g3 = 0; g3 < 3; ++g3) {
        int gc = g3*64 + jcol;
        ew0[g3] = eWih[c*384 + gc*2];
        ew1[g3] = eWih[c*384 + gc*2 + 1];
        float bi = ebih[c*192 + gc], bh = ebhh[c*192 + gc];
        ebs[g3] = bi + bh;            // used for r,z
        if (g3 == 2) { ebi_n = bi; ebh_n = bh; }
    }

    float hreg[4];                    // h_old, C/D layout rows kg*4+r4, col jcol
#pragma unroll
    for (int r4 = 0; r4 < 4; ++r4) hreg[r4] = 0.0f;

    __syncthreads();

    // ---------------- encoder step t=0 (h=0 -> no MFMA) ----------------
#pragma unroll
    for (int r4 = 0; r4 < 4; ++r4) {
        int m = kg*4 + r4;
        float x0 = sX[m*24], x1 = sX[m*24 + 1];
        float r  = sigm(fmaf(ew0[0],x0, fmaf(ew1[0],x1, ebs[0])));
        float z  = sigm(fmaf(ew0[1],x0, fmaf(ew1[1],x1, ebs[1])));
        float nn = tanh_f(fmaf(ew0[2],x0, fmaf(ew1[2],x1, ebi_n)) + r*ebh_n);
        float hnew = nn - z*nn;       // + z*0
        hreg[r4] = hnew;
        unsigned u = __float_as_uint(hnew);
        sHhi[plane_idx(m,jcol)] = (short)(u >> 16);
        sHlo[plane_idx(m,jcol)] = f2bf_rne(hnew - bf2f_hi(u));
    }
    __syncthreads();

    // ---------------- encoder steps 1..11 ----------------
    for (int t = 1; t < 12; ++t) {
        s8v Ahi[2], Alo[2];
#pragma unroll
        for (int ch = 0; ch < 2; ++ch) {
            int idx = frag_idx(nl, ch*4 + kg);
            Ahi[ch] = *(const s8v*)&sHhi[idx];
            Alo[ch] = *(const s8v*)&sHlo[idx];
        }
        __syncthreads();              // A-reads done before h overwritten

        f4v acc[3];
#pragma unroll
        for (int g3 = 0; g3 < 3; ++g3)
#pragma unroll
            for (int r4 = 0; r4 < 4; ++r4) acc[g3][r4] = 0.0f;
#pragma unroll
        for (int g3 = 0; g3 < 3; ++g3)
#pragma unroll
            for (int ch = 0; ch < 2; ++ch) {
                acc[g3] = __builtin_amdgcn_mfma_f32_16x16x32_bf16(Ahi[ch], Bh[g3][ch], acc[g3], 0,0,0);
                acc[g3] = __builtin_amdgcn_mfma_f32_16x16x32_bf16(Alo[ch], Bh[g3][ch], acc[g3], 0,0,0);
                acc[g3] = __builtin_amdgcn_mfma_f32_16x16x32_bf16(Ahi[ch], Bl[g3][ch], acc[g3], 0,0,0);
            }

#pragma unroll
        for (int r4 = 0; r4 < 4; ++r4) {
            int m = kg*4 + r4;
            float x0 = sX[m*24 + 2*t], x1 = sX[m*24 + 2*t + 1];
            float r  = sigm(acc[0][r4] + fmaf(ew0[0],x0, fmaf(ew1[0],x1, ebs[0])));
            float z  = sigm(acc[1][r4] + fmaf(ew0[1],x0, fmaf(ew1[1],x1, ebs[1])));
            float nn = tanh_f(fmaf(ew0[2],x0, fmaf(ew1[2],x1, ebi_n)) + r*(acc[2][r4] + ebh_n));
            float hnew = nn + z*(hreg[r4] - nn);
            hreg[r4] = hnew;
            unsigned u = __float_as_uint(hnew);
            sHhi[plane_idx(m,jcol)] = (short)(u >> 16);
            sHlo[plane_idx(m,jcol)] = f2bf_rne(hnew - bf2f_hi(u));
        }
        __syncthreads();
    }

    // ---------------- switch to decoder weights ----------------
    {
        const float* __restrict__ Whh = dWhh + c*12288;
#pragma unroll
        for (int g3 = 0; g3 < 3; ++g3)
#pragma unroll
            for (int ch = 0; ch < 2; ++ch) {
                const float* p = Whh + (g3*64 + jcol)*64 + ch*32 + kg*8;
                float4 a = *(const float4*)p;
                float4 b = *(const float4*)(p + 4);
                float w[8] = {a.x,a.y,a.z,a.w,b.x,b.y,b.z,b.w};
                s8v bh, bl;
#pragma unroll
                for (int i = 0; i < 8; ++i) {
                    unsigned u = __float_as_uint(w[i]);
                    bh[i] = (short)(u >> 16);
                    bl[i] = f2bf_rne(w[i] - bf2f_hi(u));
                }
                Bh[g3][ch] = bh; Bl[g3][ch] = bl;
            }
    }
    float dwv[3], dbs[3], dbi_n, dbh_n;
#pragma unroll
    for (int g3 = 0; g3 < 3; ++g3) {
        int gc = g3*64 + jcol;
        dwv[g3] = dWih[c*192 + gc];
        float bi = dbih[c*192 + gc], bh = dbhh[c*192 + gc];
        dbs[g3] = bi + bh;
        if (g3 == 2) { dbi_n = bi; dbh_n = bh; }
    }
    const float lwl = linW[c*64 + jcol];
    const float lb  = linb[c];

    if (tid < R_) sLv[tid] = sX[tid*24 + 22];   // last observed feature 0
    __syncthreads();

    // ---------------- decoder: 12 steps ----------------
    for (int t = 0; t < 12; ++t) {
        s8v Ahi[2], Alo[2];
#pragma unroll
        for (int ch = 0; ch < 2; ++ch) {
            int idx = frag_idx(nl, ch*4 + kg);
            Ahi[ch] = *(const s8v*)&sHhi[idx];
            Alo[ch] = *(const s8v*)&sHlo[idx];
        }
        __syncthreads();

        f4v acc[3];
#pragma unroll
        for (int g3 = 0; g3 < 3; ++g3)
#pragma unroll
            for (int r4 = 0; r4 < 4; ++r4) acc[g3][r4] = 0.0f;
#pragma unroll
        for (int g3 = 0; g3 < 3; ++g3)
#pragma unroll
            for (int ch = 0; ch < 2; ++ch) {
                acc[g3] = __builtin_amdgcn_mfma_f32_16x16x32_bf16(Ahi[ch], Bh[g3][ch], acc[g3], 0,0,0);
                acc[g3] = __builtin_amdgcn_mfma_f32_16x16x32_bf16(Alo[ch], Bh[g3][ch], acc[g3], 0,0,0);
                acc[g3] = __builtin_amdgcn_mfma_f32_16x16x32_bf16(Ahi[ch], Bl[g3][ch], acc[g3], 0,0,0);
            }

#pragma unroll
        for (int r4 = 0; r4 < 4; ++r4) {
            int m = kg*4 + r4;
            float lv = sLv[m];
            float r  = sigm(acc[0][r4] + fmaf(dwv[0], lv, dbs[0]));
            float z  = sigm(acc[1][r4] + fmaf(dwv[1], lv, dbs[1]));
            float nn = tanh_f(fmaf(dwv[2], lv, dbi_n) + r*(acc[2][r4] + dbh_n));
            float hnew = nn + z*(hreg[r4] - nn);
            hreg[r4] = hnew;
            unsigned u = __float_as_uint(hnew);
            sHhi[plane_idx(m,jcol)] = (short)(u >> 16);
            sHlo[plane_idx(m,jcol)] = f2bf_rne(hnew - bf2f_hi(u));

            // partial of v[m] over this wave's 16 columns
            float p = lwl * hnew;
            p += __shfl_xor(p, 1, 16);
            p += __shfl_xor(p, 2, 16);
            p += __shfl_xor(p, 4, 16);
            p += __shfl_xor(p, 8, 16);
            if (nl == 0) sVp[wv*R_ + m] = p;
        }
        __syncthreads();              // h planes + v partials ready

        if (tid < R_) {
            float v = sVp[tid] + sVp[R_+tid] + sVp[2*R_+tid] + sVp[3*R_+tid] + lb;
            sLv[tid] = v;
            atomicAdd(&out[(size_t)(row0 + tid)*12 + t], sWgt[tid]*v);
        }
        // next iteration's post-A-read barrier orders sLv for all waves
    }
}

extern "C" void kernel_launch(void* const* d_in, const int* in_sizes, int n_in,
                              void* d_out, int out_size, void* d_ws, size_t ws_size,
                              hipStream_t stream) {
    // 0:A 1:X 2:enc_Wih 3:enc_Whh 4:enc_bih 5:enc_bhh
    // 6:dec_Wih 7:dec_Whh 8:dec_bih 9:dec_bhh 10:lin_W 11:lin_b 12:embed
    const float* X    = (const float*)d_in[1];
    const float* eWih = (const float*)d_in[2];
    const float* eWhh = (const float*)d_in[3];
    const float* ebih = (const float*)d_in[4];
    const float* ebhh = (const float*)d_in[5];
    const float* dWih = (const float*)d_in[6];
    const float* dWhh = (const float*)d_in[7];
    const float* dbih = (const float*)d_in[8];
    const float* dbhh = (const float*)d_in[9];
    const float* linW = (const float*)d_in[10];
    const float* linb = (const float*)d_in[11];
    const float* emb  = (const float*)d_in[12];
    float* out = (float*)d_out;

    hipMemsetAsync(d_out, 0, (size_t)out_size * sizeof(float), stream);

    dim3 grid(BN_ / R_, 10);   // 650 x 10 = 6500 blocks, exact tiling
    krnn_kernel<<<grid, dim3(256), 0, stream>>>(
        X, eWih, eWhh, ebih, ebhh, dWih, dWhh, dbih, dbhh, linW, linb, emb, out);
}

// Round 5
// 422.886 us; speedup vs baseline: 6.9744x; 1.0108x over previous
//
#include <hip/hip_runtime.h>
#include <math.h>

#define N_   325
#define BN_  10400
#define R_   32            // rows per block (2 M-tiles per wave); 10400/32 = 325 exact

typedef short s8v __attribute__((ext_vector_type(8)));   // 8 bf16 (4 VGPRs)
typedef float f4v __attribute__((ext_vector_type(4)));   // 4 fp32 acc

__device__ __forceinline__ float rcp_f(float x){ return __builtin_amdgcn_rcpf(x); }
__device__ __forceinline__ float sigm(float x){ return rcp_f(1.0f + __expf(-x)); }
__device__ __forceinline__ float tanh_f(float x){
    float e = __expf(-2.0f*x);
    return (1.0f - e) * rcp_f(1.0f + e);
}
// h-plane [R_][64] bf16, 16B blocks XOR-swizzled by row.
__device__ __forceinline__ int plane_idx(int m,int k){
    return m*64 + ((((k>>3)^(m&7))<<3)|(k&7));
}
__device__ __forceinline__ int frag_idx(int m,int kb){   // kb = k/8
    return m*64 + ((kb^(m&7))<<3);
}

// Load this lane's 48-VGPR B (Whh) fragment set, truncation-split bf16.
__device__ __forceinline__ void load_B(const float* __restrict__ Whh, int jcol, int kg,
                                       s8v Bh[3][2], s8v Bl[3][2])
{
#pragma unroll
    for (int g3=0; g3<3; ++g3)
#pragma unroll
        for (int ch=0; ch<2; ++ch) {
            const float* p = Whh + (g3*64 + jcol)*64 + ch*32 + kg*8;
            float4 a = *(const float4*)p;
            float4 b = *(const float4*)(p+4);
            float w[8] = {a.x,a.y,a.z,a.w,b.x,b.y,b.z,b.w};
            s8v bh, bl;
#pragma unroll
            for (int i=0;i<8;++i){
                unsigned u = __float_as_uint(w[i]);
                bh[i] = (short)(u>>16);
                float hi = __uint_as_float(u & 0xffff0000u);
                bl[i] = (short)(__float_as_uint(w[i]-hi)>>16);  // exact remainder, trunc
            }
            Bh[g3][ch]=bh; Bl[g3][ch]=bl;
        }
}

// Block: 256 thr = 4 waves, 32 rows (2 M-tiles/wave), one cluster c.
// Wave w owns j-cols [16w,16w+16) for ALL 32 rows. B in 48 VGPRs/lane from
// global (L2-hot). h double-buffered in LDS (1 barrier/step). Decoder v:
// per-wave 16-col shfl partials -> sVp[m][wv] (double-buffered) -> after the
// step barrier every lane redundantly sums its rows' float4 (no 2nd barrier).
__global__ void __launch_bounds__(256, 4) krnn_kernel(
    const float* __restrict__ X,
    const float* __restrict__ eWih, const float* __restrict__ eWhh,
    const float* __restrict__ ebih, const float* __restrict__ ebhh,
    const float* __restrict__ dWih, const float* __restrict__ dWhh,
    const float* __restrict__ dbih, const float* __restrict__ dbhh,
    const float* __restrict__ linW, const float* __restrict__ linb,
    const float* __restrict__ embed, float* __restrict__ out)
{
    __shared__ short sHhi[2][R_*64], sHlo[2][R_*64];   // 8 KB + 8 KB
    __shared__ float2 sX2[12*R_];                      // [t][m] (x0,x1), 3 KB
    __shared__ float sWgt[R_];
    __shared__ float sVp[2][R_*4];                     // [buf][m][wv], 1 KB

    const int c    = blockIdx.y;
    const int row0 = blockIdx.x * R_;
    const int tid  = threadIdx.x;
    const int lane = tid & 63;
    const int wv   = tid >> 6;
    const int nl   = lane & 15;
    const int kg   = lane >> 4;
    const int jcol = wv*16 + nl;

    // ---------------- prologue ----------------
    for (int i = tid; i < 12*R_; i += 256) {           // sX2[t*R_+m]
        int t = i >> 5, m = i & (R_-1);
        const float* p = X + (size_t)(row0+m)*24 + 2*t;
        sX2[i] = make_float2(p[0], p[1]);
    }
    if (tid < R_) {
        int n = (row0 + tid) % N_;
        float e[10], mx = -1e30f;
#pragma unroll
        for (int cc=0; cc<10; ++cc){ e[cc]=embed[n*10+cc]; mx=fmaxf(mx,e[cc]); }
        float den = 0.0f;
#pragma unroll
        for (int cc=0; cc<10; ++cc) den += __expf(e[cc]-mx);
        sWgt[tid] = __expf(e[c]-mx) * rcp_f(den);
    }

    s8v Bh[3][2], Bl[3][2];
    load_B(eWhh + c*12288, jcol, kg, Bh, Bl);

    float ew0[3], ew1[3], ebs[3], ebi_n, ebh_n;
#pragma unroll
    for (int g3=0; g3<3; ++g3) {
        int gc = g3*64 + jcol;
        ew0[g3] = eWih[c*384 + gc*2];
        ew1[g3] = eWih[c*384 + gc*2 + 1];
        float bi = ebih[c*192 + gc], bh = ebhh[c*192 + gc];
        ebs[g3] = bi + bh;
        if (g3==2){ ebi_n = bi; ebh_n = bh; }
    }

    float hreg[2][4];                  // h_old: rows Mt*16+kg*4+r4, col jcol
#pragma unroll
    for (int Mt=0;Mt<2;++Mt)
#pragma unroll
        for (int r4=0;r4<4;++r4) hreg[Mt][r4]=0.0f;

    __syncthreads();

    // ---------------- encoder t=0 (h=0, no MFMA), writes buf 0 ----------------
#pragma unroll
    for (int Mt=0; Mt<2; ++Mt)
#pragma unroll
        for (int r4=0; r4<4; ++r4) {
            int m = Mt*16 + kg*4 + r4;
            float2 x = sX2[m];         // t=0
            float r  = sigm(fmaf(ew0[0],x.x, fmaf(ew1[0],x.y, ebs[0])));
            float z  = sigm(fmaf(ew0[1],x.x, fmaf(ew1[1],x.y, ebs[1])));
            float nn = tanh_f(fmaf(ew0[2],x.x, fmaf(ew1[2],x.y, ebi_n)) + r*ebh_n);
            float hnew = nn - z*nn;
            hreg[Mt][r4] = hnew;
            unsigned u = __float_as_uint(hnew);
            int idx = plane_idx(m,jcol);
            sHhi[0][idx] = (short)(u>>16);
            float hi = __uint_as_float(u & 0xffff0000u);
            sHlo[0][idx] = (short)(__float_as_uint(hnew-hi)>>16);
        }
    __syncthreads();

    // ---------------- encoder steps 1..11: read buf (t+1)&1, write t&1 ----------------
    for (int t = 1; t < 12; ++t) {
        const int rp = (t+1)&1, wp = t&1;
        s8v Ah[2][2], Al[2][2];
#pragma unroll
        for (int Mt=0; Mt<2; ++Mt)
#pragma unroll
            for (int ch=0; ch<2; ++ch) {
                int idx = frag_idx(Mt*16+nl, ch*4+kg);
                Ah[Mt][ch] = *(const s8v*)&sHhi[rp][idx];
                Al[Mt][ch] = *(const s8v*)&sHlo[rp][idx];
            }

        f4v acc[2][3];
#pragma unroll
        for (int Mt=0;Mt<2;++Mt)
#pragma unroll
            for (int g3=0;g3<3;++g3)
#pragma unroll
                for (int r4=0;r4<4;++r4) acc[Mt][g3][r4]=0.0f;
#pragma unroll
        for (int Mt=0;Mt<2;++Mt)
#pragma unroll
            for (int g3=0;g3<3;++g3)
#pragma unroll
                for (int ch=0;ch<2;++ch) {
                    acc[Mt][g3] = __builtin_amdgcn_mfma_f32_16x16x32_bf16(Ah[Mt][ch], Bh[g3][ch], acc[Mt][g3],0,0,0);
                    acc[Mt][g3] = __builtin_amdgcn_mfma_f32_16x16x32_bf16(Al[Mt][ch], Bh[g3][ch], acc[Mt][g3],0,0,0);
                    acc[Mt][g3] = __builtin_amdgcn_mfma_f32_16x16x32_bf16(Ah[Mt][ch], Bl[g3][ch], acc[Mt][g3],0,0,0);
                }

#pragma unroll
        for (int Mt=0;Mt<2;++Mt)
#pragma unroll
            for (int r4=0;r4<4;++r4) {
                int m = Mt*16 + kg*4 + r4;
                float2 x = sX2[t*R_ + m];
                float r  = sigm(acc[Mt][0][r4] + fmaf(ew0[0],x.x, fmaf(ew1[0],x.y, ebs[0])));
                float z  = sigm(acc[Mt][1][r4] + fmaf(ew0[1],x.x, fmaf(ew1[1],x.y, ebs[1])));
                float nn = tanh_f(fmaf(ew0[2],x.x, fmaf(ew1[2],x.y, ebi_n)) + r*(acc[Mt][2][r4] + ebh_n));
                float hnew = nn + z*(hreg[Mt][r4] - nn);
                hreg[Mt][r4] = hnew;
                unsigned u = __float_as_uint(hnew);
                int idx = plane_idx(m,jcol);
                sHhi[wp][idx] = (short)(u>>16);
                float hi = __uint_as_float(u & 0xffff0000u);
                sHlo[wp][idx] = (short)(__float_as_uint(hnew-hi)>>16);
            }
        __syncthreads();
    }

    // ---------------- decoder setup ----------------
    load_B(dWhh + c*12288, jcol, kg, Bh, Bl);
    float dwv[3], dbs[3], dbi_n, dbh_n;
#pragma unroll
    for (int g3=0; g3<3; ++g3) {
        int gc = g3*64 + jcol;
        dwv[g3] = dWih[c*192 + gc];
        float bi = dbih[c*192 + gc], bh = dbhh[c*192 + gc];
        dbs[g3] = bi + bh;
        if (g3==2){ dbi_n = bi; dbh_n = bh; }
    }
    const float lwl = linW[c*64 + jcol];
    const float lb  = linb[c];

    float vlv[2][4], wgtr[2][4];
#pragma unroll
    for (int Mt=0;Mt<2;++Mt)
#pragma unroll
        for (int r4=0;r4<4;++r4) {
            int m = Mt*16 + kg*4 + r4;
            vlv[Mt][r4]  = sX2[11*R_ + m].x;   // last observed feature 0
            wgtr[Mt][r4] = sWgt[m];
        }

    // ---------------- decoder: 12 steps, read buf (s+1)&1, write s&1 ----------------
    for (int s = 0; s < 12; ++s) {
        const int rp = (s+1)&1, wp = s&1;
        s8v Ah[2][2], Al[2][2];
#pragma unroll
        for (int Mt=0; Mt<2; ++Mt)
#pragma unroll
            for (int ch=0; ch<2; ++ch) {
                int idx = frag_idx(Mt*16+nl, ch*4+kg);
                Ah[Mt][ch] = *(const s8v*)&sHhi[rp][idx];
                Al[Mt][ch] = *(const s8v*)&sHlo[rp][idx];
            }

        f4v acc[2][3];
#pragma unroll
        for (int Mt=0;Mt<2;++Mt)
#pragma unroll
            for (int g3=0;g3<3;++g3)
#pragma unroll
                for (int r4=0;r4<4;++r4) acc[Mt][g3][r4]=0.0f;
#pragma unroll
        for (int Mt=0;Mt<2;++Mt)
#pragma unroll
            for (int g3=0;g3<3;++g3)
#pragma unroll
                for (int ch=0;ch<2;++ch) {
                    acc[Mt][g3] = __builtin_amdgcn_mfma_f32_16x16x32_bf16(Ah[Mt][ch], Bh[g3][ch], acc[Mt][g3],0,0,0);
                    acc[Mt][g3] = __builtin_amdgcn_mfma_f32_16x16x32_bf16(Al[Mt][ch], Bh[g3][ch], acc[Mt][g3],0,0,0);
                    acc[Mt][g3] = __builtin_amdgcn_mfma_f32_16x16x32_bf16(Ah[Mt][ch], Bl[g3][ch], acc[Mt][g3],0,0,0);
                }

#pragma unroll
        for (int Mt=0;Mt<2;++Mt)
#pragma unroll
            for (int r4=0;r4<4;++r4) {
                int m = Mt*16 + kg*4 + r4;
                float lv = vlv[Mt][r4];
                float r  = sigm(acc[Mt][0][r4] + fmaf(dwv[0], lv, dbs[0]));
                float z  = sigm(acc[Mt][1][r4] + fmaf(dwv[1], lv, dbs[1]));
                float nn = tanh_f(fmaf(dwv[2], lv, dbi_n) + r*(acc[Mt][2][r4] + dbh_n));
                float hnew = nn + z*(hreg[Mt][r4] - nn);
                hreg[Mt][r4] = hnew;
                unsigned u = __float_as_uint(hnew);
                int idx = plane_idx(m,jcol);
                sHhi[wp][idx] = (short)(u>>16);
                float hi = __uint_as_float(u & 0xffff0000u);
                sHlo[wp][idx] = (short)(__float_as_uint(hnew-hi)>>16);

                float p = lwl * hnew;               // partial over this wave's 16 cols
                p += __shfl_xor(p, 1, 16);
                p += __shfl_xor(p, 2, 16);
                p += __shfl_xor(p, 4, 16);
                p += __shfl_xor(p, 8, 16);
                if (nl == 0) sVp[wp][m*4 + wv] = p;
            }
        __syncthreads();   // h planes + v partials ready (single barrier/step)

        // every lane redundantly finalizes v for its 8 rows (float4 broadcast reads)
#pragma unroll
        for (int Mt=0;Mt<2;++Mt)
#pragma unroll
            for (int r4=0;r4<4;++r4) {
                int m = Mt*16 + kg*4 + r4;
                float4 q = *(const float4*)&sVp[wp][m*4];
                float v = (q.x + q.y) + (q.z + q.w) + lb;
                vlv[Mt][r4] = v;
                if (wv == 0 && nl == 0)
                    atomicAdd(&out[(size_t)(row0+m)*12 + s], wgtr[Mt][r4]*v);
            }
        // sVp buffer alternates (wp) -> step s+2's writes can't race step s's reads
    }
}

extern "C" void kernel_launch(void* const* d_in, const int* in_sizes, int n_in,
                              void* d_out, int out_size, void* d_ws, size_t ws_size,
                              hipStream_t stream) {
    // 0:A 1:X 2:enc_Wih 3:enc_Whh 4:enc_bih 5:enc_bhh
    // 6:dec_Wih 7:dec_Whh 8:dec_bih 9:dec_bhh 10:lin_W 11:lin_b 12:embed
    const float* X    = (const float*)d_in[1];
    const float* eWih = (const float*)d_in[2];
    const float* eWhh = (const float*)d_in[3];
    const float* ebih = (const float*)d_in[4];
    const float* ebhh = (const float*)d_in[5];
    const float* dWih = (const float*)d_in[6];
    const float* dWhh = (const float*)d_in[7];
    const float* dbih = (const float*)d_in[8];
    const float* dbhh = (const float*)d_in[9];
    const float* linW = (const float*)d_in[10];
    const float* linb = (const float*)d_in[11];
    const float* emb  = (const float*)d_in[12];
    float* out = (float*)d_out;

    hipMemsetAsync(d_out, 0, (size_t)out_size * sizeof(float), stream);

    dim3 grid(BN_ / R_, 10);   // 325 x 10 blocks
    krnn_kernel<<<grid, dim3(256), 0, stream>>>(
        X, eWih, eWhh, ebih, ebhh, dWih, dWhh, dbih, dbhh, linW, linb, emb, out);
}

// Round 6
// 349.281 us; speedup vs baseline: 8.4442x; 1.2107x over previous
//
#include <hip/hip_runtime.h>
#include <math.h>

#define N_   325
#define BN_  10400
#define R_   32            // rows per block (2 M-tiles per wave); 10400/32 = 325 exact

typedef short s8v __attribute__((ext_vector_type(8)));   // 8 bf16 (4 VGPRs)
typedef float f4v __attribute__((ext_vector_type(4)));   // 4 fp32 acc

__device__ __forceinline__ float rcp_f(float x){ return __builtin_amdgcn_rcpf(x); }
__device__ __forceinline__ float sigm(float x){ return rcp_f(1.0f + __expf(-x)); }
__device__ __forceinline__ float tanh_f(float x){
    float e = __expf(-2.0f*x);
    return (1.0f - e) * rcp_f(1.0f + e);
}
// h-plane [R_][64] bf16, 16B blocks XOR-swizzled by row.
__device__ __forceinline__ int plane_idx(int m,int k){
    return m*64 + ((((k>>3)^(m&7))<<3)|(k&7));
}
__device__ __forceinline__ int frag_idx(int m,int kb){   // kb = k/8
    return m*64 + ((kb^(m&7))<<3);
}

// Load this lane's 48-VGPR B (Whh) fragment set, truncation-split bf16.
__device__ __forceinline__ void load_B(const float* __restrict__ Whh, int jcol, int kg,
                                       s8v Bh[3][2], s8v Bl[3][2])
{
#pragma unroll
    for (int g3=0; g3<3; ++g3)
#pragma unroll
        for (int ch=0; ch<2; ++ch) {
            const float* p = Whh + (g3*64 + jcol)*64 + ch*32 + kg*8;
            float4 a = *(const float4*)p;
            float4 b = *(const float4*)(p+4);
            float w[8] = {a.x,a.y,a.z,a.w,b.x,b.y,b.z,b.w};
            s8v bh, bl;
#pragma unroll
            for (int i=0;i<8;++i){
                unsigned u = __float_as_uint(w[i]);
                bh[i] = (short)(u>>16);
                float hi = __uint_as_float(u & 0xffff0000u);
                bl[i] = (short)(__float_as_uint(w[i]-hi)>>16);  // exact remainder, trunc
            }
            Bh[g3][ch]=bh; Bl[g3][ch]=bl;
        }
}

// Block: 256 thr = 4 waves, 32 rows (2 M-tiles/wave), one cluster c.
// Wave w owns j-cols [16w,16w+16) for ALL 32 rows. B in 48 VGPRs/lane from
// global (L2-hot). h double-buffered in LDS (1 barrier/step).
// __launch_bounds__(256,3): ~168 unified regs/lane -> no scratch spill
// (R5's (256,4) cap of 128 caused 110 MB/dispatch spill traffic); 3 waves/EU
// matches the 12 waves/CU the HW achieved anyway.
__global__ void __launch_bounds__(256, 3) krnn_kernel(
    const float* __restrict__ X,
    const float* __restrict__ eWih, const float* __restrict__ eWhh,
    const float* __restrict__ ebih, const float* __restrict__ ebhh,
    const float* __restrict__ dWih, const float* __restrict__ dWhh,
    const float* __restrict__ dbih, const float* __restrict__ dbhh,
    const float* __restrict__ linW, const float* __restrict__ linb,
    const float* __restrict__ embed, float* __restrict__ out)
{
    __shared__ short sHhi[2][R_*64], sHlo[2][R_*64];   // 8 KB + 8 KB
    __shared__ float2 sX2[12*R_];                      // [t][m] (x0,x1), 3 KB
    __shared__ float sWgt[R_];
    __shared__ float sVp[2][R_*4];                     // [buf][m][wv], 1 KB

    const int c    = blockIdx.y;
    const int row0 = blockIdx.x * R_;
    const int tid  = threadIdx.x;
    const int lane = tid & 63;
    const int wv   = tid >> 6;
    const int nl   = lane & 15;
    const int kg   = lane >> 4;
    const int jcol = wv*16 + nl;

    // ---------------- prologue ----------------
    for (int i = tid; i < 12*R_; i += 256) {           // sX2[t*R_+m]
        int t = i >> 5, m = i & (R_-1);
        const float* p = X + (size_t)(row0+m)*24 + 2*t;
        sX2[i] = make_float2(p[0], p[1]);
    }
    if (tid < R_) {
        int n = (row0 + tid) % N_;
        float e[10], mx = -1e30f;
#pragma unroll
        for (int cc=0; cc<10; ++cc){ e[cc]=embed[n*10+cc]; mx=fmaxf(mx,e[cc]); }
        float den = 0.0f;
#pragma unroll
        for (int cc=0; cc<10; ++cc) den += __expf(e[cc]-mx);
        sWgt[tid] = __expf(e[c]-mx) * rcp_f(den);
    }

    s8v Bh[3][2], Bl[3][2];
    load_B(eWhh + c*12288, jcol, kg, Bh, Bl);

    float ew0[3], ew1[3], ebs[3], ebi_n, ebh_n;
#pragma unroll
    for (int g3=0; g3<3; ++g3) {
        int gc = g3*64 + jcol;
        ew0[g3] = eWih[c*384 + gc*2];
        ew1[g3] = eWih[c*384 + gc*2 + 1];
        float bi = ebih[c*192 + gc], bh = ebhh[c*192 + gc];
        ebs[g3] = bi + bh;
        if (g3==2){ ebi_n = bi; ebh_n = bh; }
    }

    float hreg[2][4];                  // h_old: rows Mt*16+kg*4+r4, col jcol
#pragma unroll
    for (int Mt=0;Mt<2;++Mt)
#pragma unroll
        for (int r4=0;r4<4;++r4) hreg[Mt][r4]=0.0f;

    __syncthreads();

    // ---------------- encoder t=0 (h=0, no MFMA), writes buf 0 ----------------
#pragma unroll
    for (int Mt=0; Mt<2; ++Mt)
#pragma unroll
        for (int r4=0; r4<4; ++r4) {
            int m = Mt*16 + kg*4 + r4;
            float2 x = sX2[m];         // t=0
            float r  = sigm(fmaf(ew0[0],x.x, fmaf(ew1[0],x.y, ebs[0])));
            float z  = sigm(fmaf(ew0[1],x.x, fmaf(ew1[1],x.y, ebs[1])));
            float nn = tanh_f(fmaf(ew0[2],x.x, fmaf(ew1[2],x.y, ebi_n)) + r*ebh_n);
            float hnew = nn - z*nn;
            hreg[Mt][r4] = hnew;
            unsigned u = __float_as_uint(hnew);
            int idx = plane_idx(m,jcol);
            sHhi[0][idx] = (short)(u>>16);
            float hi = __uint_as_float(u & 0xffff0000u);
            sHlo[0][idx] = (short)(__float_as_uint(hnew-hi)>>16);
        }
    __syncthreads();

    // ---------------- encoder steps 1..11: read buf (t+1)&1, write t&1 ----------------
    for (int t = 1; t < 12; ++t) {
        const int rp = (t+1)&1, wp = t&1;
        s8v Ah[2][2], Al[2][2];
#pragma unroll
        for (int Mt=0; Mt<2; ++Mt)
#pragma unroll
            for (int ch=0; ch<2; ++ch) {
                int idx = frag_idx(Mt*16+nl, ch*4+kg);
                Ah[Mt][ch] = *(const s8v*)&sHhi[rp][idx];
                Al[Mt][ch] = *(const s8v*)&sHlo[rp][idx];
            }

        f4v acc[2][3];
#pragma unroll
        for (int Mt=0;Mt<2;++Mt)
#pragma unroll
            for (int g3=0;g3<3;++g3)
#pragma unroll
                for (int r4=0;r4<4;++r4) acc[Mt][g3][r4]=0.0f;
#pragma unroll
        for (int Mt=0;Mt<2;++Mt)
#pragma unroll
            for (int g3=0;g3<3;++g3)
#pragma unroll
                for (int ch=0;ch<2;++ch) {
                    acc[Mt][g3] = __builtin_amdgcn_mfma_f32_16x16x32_bf16(Ah[Mt][ch], Bh[g3][ch], acc[Mt][g3],0,0,0);
                    acc[Mt][g3] = __builtin_amdgcn_mfma_f32_16x16x32_bf16(Al[Mt][ch], Bh[g3][ch], acc[Mt][g3],0,0,0);
                    acc[Mt][g3] = __builtin_amdgcn_mfma_f32_16x16x32_bf16(Ah[Mt][ch], Bl[g3][ch], acc[Mt][g3],0,0,0);
                }

#pragma unroll
        for (int Mt=0;Mt<2;++Mt)
#pragma unroll
            for (int r4=0;r4<4;++r4) {
                int m = Mt*16 + kg*4 + r4;
                float2 x = sX2[t*R_ + m];
                float r  = sigm(acc[Mt][0][r4] + fmaf(ew0[0],x.x, fmaf(ew1[0],x.y, ebs[0])));
                float z  = sigm(acc[Mt][1][r4] + fmaf(ew0[1],x.x, fmaf(ew1[1],x.y, ebs[1])));
                float nn = tanh_f(fmaf(ew0[2],x.x, fmaf(ew1[2],x.y, ebi_n)) + r*(acc[Mt][2][r4] + ebh_n));
                float hnew = nn + z*(hreg[Mt][r4] - nn);
                hreg[Mt][r4] = hnew;
                unsigned u = __float_as_uint(hnew);
                int idx = plane_idx(m,jcol);
                sHhi[wp][idx] = (short)(u>>16);
                float hi = __uint_as_float(u & 0xffff0000u);
                sHlo[wp][idx] = (short)(__float_as_uint(hnew-hi)>>16);
            }
        __syncthreads();
    }

    // ---------------- decoder setup ----------------
    load_B(dWhh + c*12288, jcol, kg, Bh, Bl);
    float dwv[3], dbs[3], dbi_n, dbh_n;
#pragma unroll
    for (int g3=0; g3<3; ++g3) {
        int gc = g3*64 + jcol;
        dwv[g3] = dWih[c*192 + gc];
        float bi = dbih[c*192 + gc], bh = dbhh[c*192 + gc];
        dbs[g3] = bi + bh;
        if (g3==2){ dbi_n = bi; dbh_n = bh; }
    }
    const float lwl = linW[c*64 + jcol];
    const float lb  = linb[c];

    float vlv[2][4];
#pragma unroll
    for (int Mt=0;Mt<2;++Mt)
#pragma unroll
        for (int r4=0;r4<4;++r4) {
            int m = Mt*16 + kg*4 + r4;
            vlv[Mt][r4] = sX2[11*R_ + m].x;   // last observed feature 0
        }

    // ---------------- decoder: 12 steps, read buf (s+1)&1, write s&1 ----------------
    for (int s = 0; s < 12; ++s) {
        const int rp = (s+1)&1, wp = s&1;
        s8v Ah[2][2], Al[2][2];
#pragma unroll
        for (int Mt=0; Mt<2; ++Mt)
#pragma unroll
            for (int ch=0; ch<2; ++ch) {
                int idx = frag_idx(Mt*16+nl, ch*4+kg);
                Ah[Mt][ch] = *(const s8v*)&sHhi[rp][idx];
                Al[Mt][ch] = *(const s8v*)&sHlo[rp][idx];
            }

        f4v acc[2][3];
#pragma unroll
        for (int Mt=0;Mt<2;++Mt)
#pragma unroll
            for (int g3=0;g3<3;++g3)
#pragma unroll
                for (int r4=0;r4<4;++r4) acc[Mt][g3][r4]=0.0f;
#pragma unroll
        for (int Mt=0;Mt<2;++Mt)
#pragma unroll
            for (int g3=0;g3<3;++g3)
#pragma unroll
                for (int ch=0;ch<2;++ch) {
                    acc[Mt][g3] = __builtin_amdgcn_mfma_f32_16x16x32_bf16(Ah[Mt][ch], Bh[g3][ch], acc[Mt][g3],0,0,0);
                    acc[Mt][g3] = __builtin_amdgcn_mfma_f32_16x16x32_bf16(Al[Mt][ch], Bh[g3][ch], acc[Mt][g3],0,0,0);
                    acc[Mt][g3] = __builtin_amdgcn_mfma_f32_16x16x32_bf16(Ah[Mt][ch], Bl[g3][ch], acc[Mt][g3],0,0,0);
                }

#pragma unroll
        for (int Mt=0;Mt<2;++Mt)
#pragma unroll
            for (int r4=0;r4<4;++r4) {
                int m = Mt*16 + kg*4 + r4;
                float lv = vlv[Mt][r4];
                float r  = sigm(acc[Mt][0][r4] + fmaf(dwv[0], lv, dbs[0]));
                float z  = sigm(acc[Mt][1][r4] + fmaf(dwv[1], lv, dbs[1]));
                float nn = tanh_f(fmaf(dwv[2], lv, dbi_n) + r*(acc[Mt][2][r4] + dbh_n));
                float hnew = nn + z*(hreg[Mt][r4] - nn);
                hreg[Mt][r4] = hnew;
                unsigned u = __float_as_uint(hnew);
                int idx = plane_idx(m,jcol);
                sHhi[wp][idx] = (short)(u>>16);
                float hi = __uint_as_float(u & 0xffff0000u);
                sHlo[wp][idx] = (short)(__float_as_uint(hnew-hi)>>16);

                float p = lwl * hnew;               // partial over this wave's 16 cols
                p += __shfl_xor(p, 1, 16);
                p += __shfl_xor(p, 2, 16);
                p += __shfl_xor(p, 4, 16);
                p += __shfl_xor(p, 8, 16);
                if (nl == 0) sVp[wp][m*4 + wv] = p;
            }
        __syncthreads();   // h planes + v partials ready (single barrier/step)

        // every lane redundantly finalizes v for its 8 rows (float4 broadcast reads)
#pragma unroll
        for (int Mt=0;Mt<2;++Mt)
#pragma unroll
            for (int r4=0;r4<4;++r4) {
                int m = Mt*16 + kg*4 + r4;
                float4 q = *(const float4*)&sVp[wp][m*4];
                float v = (q.x + q.y) + (q.z + q.w) + lb;
                vlv[Mt][r4] = v;
                if (wv == 0 && nl == 0)
                    atomicAdd(&out[(size_t)(row0+m)*12 + s], sWgt[m]*v);
            }
        // sVp buffer alternates (wp) -> step s+2's writes can't race step s's reads
    }
}

extern "C" void kernel_launch(void* const* d_in, const int* in_sizes, int n_in,
                              void* d_out, int out_size, void* d_ws, size_t ws_size,
                              hipStream_t stream) {
    // 0:A 1:X 2:enc_Wih 3:enc_Whh 4:enc_bih 5:enc_bhh
    // 6:dec_Wih 7:dec_Whh 8:dec_bih 9:dec_bhh 10:lin_W 11:lin_b 12:embed
    const float* X    = (const float*)d_in[1];
    const float* eWih = (const float*)d_in[2];
    const float* eWhh = (const float*)d_in[3];
    const float* ebih = (const float*)d_in[4];
    const float* ebhh = (const float*)d_in[5];
    const float* dWih = (const float*)d_in[6];
    const float* dWhh = (const float*)d_in[7];
    const float* dbih = (const float*)d_in[8];
    const float* dbhh = (const float*)d_in[9];
    const float* linW = (const float*)d_in[10];
    const float* linb = (const float*)d_in[11];
    const float* emb  = (const float*)d_in[12];
    float* out = (float*)d_out;

    hipMemsetAsync(d_out, 0, (size_t)out_size * sizeof(float), stream);

    dim3 grid(BN_ / R_, 10);   // 325 x 10 blocks
    krnn_kernel<<<grid, dim3(256), 0, stream>>>(
        X, eWih, eWhh, ebih, ebhh, dWih, dWhh, dbih, dbhh, linW, linb, emb, out);
}

// Round 7
// 270.858 us; speedup vs baseline: 10.8891x; 1.2895x over previous
//
#include <hip/hip_runtime.h>
#include <math.h>

#define N_   325
#define BN_  10400
#define R_   32            // rows per block (2 M-tiles per wave); 10400/32 = 325 exact

typedef _Float16 h8v __attribute__((ext_vector_type(8)));  // 8 f16 (4 VGPRs)
typedef float    f4v __attribute__((ext_vector_type(4)));  // 4 fp32 acc

#define L1C  1.4426950408889634f    // log2(e)
#define L2C  2.8853900817779268f    // 2*log2(e)

__device__ __forceinline__ float rcp_f(float x){ return __builtin_amdgcn_rcpf(x); }
#if __has_builtin(__builtin_amdgcn_exp2f)
__device__ __forceinline__ float exp2_f(float x){ return __builtin_amdgcn_exp2f(x); }
#else
__device__ __forceinline__ float exp2_f(float x){ return __expf(x * 0.6931471805599453f); }
#endif

// h-plane [R_][64] f16, 16B blocks XOR-swizzled by row.
__device__ __forceinline__ int plane_idx(int m,int k){
    return m*64 + ((((k>>3)^(m&7))<<3)|(k&7));
}
__device__ __forceinline__ int frag_idx(int m,int kb){   // kb = k/8
    return m*64 + ((kb^(m&7))<<3);
}

// Load this lane's 24-VGPR B (Whh) fragment set, fp16 single-precision-pass.
__device__ __forceinline__ void load_B(const float* __restrict__ Whh, int jcol, int kg,
                                       h8v Bf[3][2])
{
#pragma unroll
    for (int g3=0; g3<3; ++g3)
#pragma unroll
        for (int ch=0; ch<2; ++ch) {
            const float* p = Whh + (g3*64 + jcol)*64 + ch*32 + kg*8;
            float4 a = *(const float4*)p;
            float4 b = *(const float4*)(p+4);
            h8v v;
            v[0]=(_Float16)a.x; v[1]=(_Float16)a.y; v[2]=(_Float16)a.z; v[3]=(_Float16)a.w;
            v[4]=(_Float16)b.x; v[5]=(_Float16)b.y; v[6]=(_Float16)b.z; v[7]=(_Float16)b.w;
            Bf[g3][ch] = v;
        }
}

// Block: 256 thr = 4 waves, 32 rows (2 M-tiles/wave), one cluster c.
// Wave w owns j-cols [16w,16w+16) for all rows. Single-pass fp16 MFMA
// (gh = h*Whh^T); the recurrence carry hreg stays fp32 in registers, so fp16
// error only perturbs gh per step (~1.6e-4), it does not compound via z*h.
// Gate math uses exp2 with -log2e folded into pre-scaled constants.
// h single fp16 plane, double-buffered (1 barrier/step).
__global__ void __launch_bounds__(256, 3) krnn_kernel(
    const float* __restrict__ X,
    const float* __restrict__ eWih, const float* __restrict__ eWhh,
    const float* __restrict__ ebih, const float* __restrict__ ebhh,
    const float* __restrict__ dWih, const float* __restrict__ dWhh,
    const float* __restrict__ dbih, const float* __restrict__ dbhh,
    const float* __restrict__ linW, const float* __restrict__ linb,
    const float* __restrict__ embed, float* __restrict__ out)
{
    __shared__ _Float16 sH[2][R_*64];                  // 8 KB
    __shared__ float2 sX2[12*R_];                      // [t][m] (x0,x1), 3 KB
    __shared__ float sWgt[R_];
    __shared__ float sVp[2][R_*4];                     // [buf][m][wv], 1 KB

    const int c    = blockIdx.y;
    const int row0 = blockIdx.x * R_;
    const int tid  = threadIdx.x;
    const int lane = tid & 63;
    const int wv   = tid >> 6;
    const int nl   = lane & 15;
    const int kg   = lane >> 4;
    const int jcol = wv*16 + nl;

    // ---------------- prologue ----------------
    for (int i = tid; i < 12*R_; i += 256) {           // sX2[t*R_+m]
        int t = i >> 5, m = i & (R_-1);
        const float* p = X + (size_t)(row0+m)*24 + 2*t;
        sX2[i] = make_float2(p[0], p[1]);
    }
    if (tid < R_) {
        int n = (row0 + tid) % N_;
        float e[10], mx = -1e30f;
#pragma unroll
        for (int cc=0; cc<10; ++cc){ e[cc]=embed[n*10+cc]; mx=fmaxf(mx,e[cc]); }
        float den = 0.0f;
#pragma unroll
        for (int cc=0; cc<10; ++cc) den += exp2_f((e[cc]-mx)*L1C);
        sWgt[tid] = exp2_f((e[c]-mx)*L1C) * rcp_f(den);
    }

    h8v Bf[3][2];
    load_B(eWhh + c*12288, jcol, kg, Bf);

    // pre-scaled encoder gate constants for this lane's column
    // r,z: arg_scaled = -L1*(acc + gi)  -> gis = fmaf(ew_s, x, ebs_s), then fmaf(acc,-L1,gis)
    // n:   a_s2 = -2L1*(gin + r*q)     -> gin_s2 pre-scaled, q = acc + ebh_n raw
    float ew0s[2], ew1s[2], ebss[2];      // r,z scaled by -L1
    float ew0n2, ew1n2, ebin2, ebh_n;     // n path
    {
        int gc = jcol;
        ew0s[0] = -L1C*eWih[c*384 + gc*2];  ew1s[0] = -L1C*eWih[c*384 + gc*2 + 1];
        ebss[0] = -L1C*(ebih[c*192 + gc] + ebhh[c*192 + gc]);
        gc = 64 + jcol;
        ew0s[1] = -L1C*eWih[c*384 + gc*2];  ew1s[1] = -L1C*eWih[c*384 + gc*2 + 1];
        ebss[1] = -L1C*(ebih[c*192 + gc] + ebhh[c*192 + gc]);
        gc = 128 + jcol;
        ew0n2 = -L2C*eWih[c*384 + gc*2];    ew1n2 = -L2C*eWih[c*384 + gc*2 + 1];
        ebin2 = -L2C*ebih[c*192 + gc];
        ebh_n = ebhh[c*192 + gc];
    }

    float hreg[2][4];                  // h_old (fp32 carry): rows Mt*16+kg*4+r4, col jcol
#pragma unroll
    for (int Mt=0;Mt<2;++Mt)
#pragma unroll
        for (int r4=0;r4<4;++r4) hreg[Mt][r4]=0.0f;

    __syncthreads();

    // ---------------- encoder t=0 (h=0, no MFMA), writes buf 0 ----------------
#pragma unroll
    for (int Mt=0; Mt<2; ++Mt)
#pragma unroll
        for (int r4=0; r4<4; ++r4) {
            int m = Mt*16 + kg*4 + r4;
            float2 x = sX2[m];         // t=0
            float r  = rcp_f(1.0f + exp2_f(fmaf(ew0s[0],x.x, fmaf(ew1s[0],x.y, ebss[0]))));
            float z  = rcp_f(1.0f + exp2_f(fmaf(ew0s[1],x.x, fmaf(ew1s[1],x.y, ebss[1]))));
            float gin2 = fmaf(ew0n2,x.x, fmaf(ew1n2,x.y, ebin2));
            float e  = exp2_f(fmaf(r*ebh_n, -L2C, gin2));
            float nn = fmaf(2.0f, rcp_f(1.0f + e), -1.0f);
            float hnew = nn - z*nn;
            hreg[Mt][r4] = hnew;
            sH[0][plane_idx(m,jcol)] = (_Float16)hnew;
        }
    __syncthreads();

    // ---------------- encoder steps 1..11: read buf (t+1)&1, write t&1 ----------------
    for (int t = 1; t < 12; ++t) {
        const int rp = (t+1)&1, wp = t&1;
        h8v Ah[2][2];
#pragma unroll
        for (int Mt=0; Mt<2; ++Mt)
#pragma unroll
            for (int ch=0; ch<2; ++ch)
                Ah[Mt][ch] = *(const h8v*)&sH[rp][frag_idx(Mt*16+nl, ch*4+kg)];

        f4v acc[2][3];
#pragma unroll
        for (int Mt=0;Mt<2;++Mt)
#pragma unroll
            for (int g3=0;g3<3;++g3)
#pragma unroll
                for (int r4=0;r4<4;++r4) acc[Mt][g3][r4]=0.0f;
#pragma unroll
        for (int Mt=0;Mt<2;++Mt)
#pragma unroll
            for (int g3=0;g3<3;++g3)
#pragma unroll
                for (int ch=0;ch<2;++ch)
                    acc[Mt][g3] = __builtin_amdgcn_mfma_f32_16x16x32_f16(Ah[Mt][ch], Bf[g3][ch], acc[Mt][g3],0,0,0);

#pragma unroll
        for (int Mt=0;Mt<2;++Mt)
#pragma unroll
            for (int r4=0;r4<4;++r4) {
                int m = Mt*16 + kg*4 + r4;
                float2 x = sX2[t*R_ + m];
                float gisr = fmaf(ew0s[0],x.x, fmaf(ew1s[0],x.y, ebss[0]));
                float gisz = fmaf(ew0s[1],x.x, fmaf(ew1s[1],x.y, ebss[1]));
                float r  = rcp_f(1.0f + exp2_f(fmaf(acc[Mt][0][r4], -L1C, gisr)));
                float z  = rcp_f(1.0f + exp2_f(fmaf(acc[Mt][1][r4], -L1C, gisz)));
                float gin2 = fmaf(ew0n2,x.x, fmaf(ew1n2,x.y, ebin2));
                float q  = acc[Mt][2][r4] + ebh_n;
                float e  = exp2_f(fmaf(r*q, -L2C, gin2));
                float nn = fmaf(2.0f, rcp_f(1.0f + e), -1.0f);
                float hnew = nn + z*(hreg[Mt][r4] - nn);
                hreg[Mt][r4] = hnew;
                sH[wp][plane_idx(m,jcol)] = (_Float16)hnew;
            }
        __syncthreads();
    }

    // ---------------- decoder setup ----------------
    load_B(dWhh + c*12288, jcol, kg, Bf);
    float dws[2], dbss[2], dwn2, dbin2, dbh_n;
    {
        int gc = jcol;
        dws[0]  = -L1C*dWih[c*192 + gc];
        dbss[0] = -L1C*(dbih[c*192 + gc] + dbhh[c*192 + gc]);
        gc = 64 + jcol;
        dws[1]  = -L1C*dWih[c*192 + gc];
        dbss[1] = -L1C*(dbih[c*192 + gc] + dbhh[c*192 + gc]);
        gc = 128 + jcol;
        dwn2  = -L2C*dWih[c*192 + gc];
        dbin2 = -L2C*dbih[c*192 + gc];
        dbh_n = dbhh[c*192 + gc];
    }
    const float lwl = linW[c*64 + jcol];
    const float lb  = linb[c];

    float vlv[2][4];
#pragma unroll
    for (int Mt=0;Mt<2;++Mt)
#pragma unroll
        for (int r4=0;r4<4;++r4)
            vlv[Mt][r4] = sX2[11*R_ + Mt*16 + kg*4 + r4].x;   // last observed feature 0

    // ---------------- decoder: 12 steps, read buf (s+1)&1, write s&1 ----------------
    for (int s = 0; s < 12; ++s) {
        const int rp = (s+1)&1, wp = s&1;
        h8v Ah[2][2];
#pragma unroll
        for (int Mt=0; Mt<2; ++Mt)
#pragma unroll
            for (int ch=0; ch<2; ++ch)
                Ah[Mt][ch] = *(const h8v*)&sH[rp][frag_idx(Mt*16+nl, ch*4+kg)];

        f4v acc[2][3];
#pragma unroll
        for (int Mt=0;Mt<2;++Mt)
#pragma unroll
            for (int g3=0;g3<3;++g3)
#pragma unroll
                for (int r4=0;r4<4;++r4) acc[Mt][g3][r4]=0.0f;
#pragma unroll
        for (int Mt=0;Mt<2;++Mt)
#pragma unroll
            for (int g3=0;g3<3;++g3)
#pragma unroll
                for (int ch=0;ch<2;++ch)
                    acc[Mt][g3] = __builtin_amdgcn_mfma_f32_16x16x32_f16(Ah[Mt][ch], Bf[g3][ch], acc[Mt][g3],0,0,0);

#pragma unroll
        for (int Mt=0;Mt<2;++Mt)
#pragma unroll
            for (int r4=0;r4<4;++r4) {
                int m = Mt*16 + kg*4 + r4;
                float lv = vlv[Mt][r4];
                float r  = rcp_f(1.0f + exp2_f(fmaf(acc[Mt][0][r4], -L1C, fmaf(dws[0], lv, dbss[0]))));
                float z  = rcp_f(1.0f + exp2_f(fmaf(acc[Mt][1][r4], -L1C, fmaf(dws[1], lv, dbss[1]))));
                float q  = acc[Mt][2][r4] + dbh_n;
                float e  = exp2_f(fmaf(r*q, -L2C, fmaf(dwn2, lv, dbin2)));
                float nn = fmaf(2.0f, rcp_f(1.0f + e), -1.0f);
                float hnew = nn + z*(hreg[Mt][r4] - nn);
                hreg[Mt][r4] = hnew;
                sH[wp][plane_idx(m,jcol)] = (_Float16)hnew;

                float p = lwl * hnew;               // partial over this wave's 16 cols
                p += __shfl_xor(p, 1, 16);
                p += __shfl_xor(p, 2, 16);
                p += __shfl_xor(p, 4, 16);
                p += __shfl_xor(p, 8, 16);
                if (nl == 0) sVp[wp][m*4 + wv] = p;
            }
        __syncthreads();   // h plane + v partials ready (single barrier/step)

        // every lane redundantly finalizes v for its 8 rows (float4 broadcast reads)
#pragma unroll
        for (int Mt=0;Mt<2;++Mt)
#pragma unroll
            for (int r4=0;r4<4;++r4) {
                int m = Mt*16 + kg*4 + r4;
                float4 qv = *(const float4*)&sVp[wp][m*4];
                float v = (qv.x + qv.y) + (qv.z + qv.w) + lb;
                vlv[Mt][r4] = v;
                if (wv == 0 && nl == 0)
                    atomicAdd(&out[(size_t)(row0+m)*12 + s], sWgt[m]*v);
            }
        // sVp buffer alternates (wp) -> step s+2's writes can't race step s's reads
    }
}

extern "C" void kernel_launch(void* const* d_in, const int* in_sizes, int n_in,
                              void* d_out, int out_size, void* d_ws, size_t ws_size,
                              hipStream_t stream) {
    // 0:A 1:X 2:enc_Wih 3:enc_Whh 4:enc_bih 5:enc_bhh
    // 6:dec_Wih 7:dec_Whh 8:dec_bih 9:dec_bhh 10:lin_W 11:lin_b 12:embed
    const float* X    = (const float*)d_in[1];
    const float* eWih = (const float*)d_in[2];
    const float* eWhh = (const float*)d_in[3];
    const float* ebih = (const float*)d_in[4];
    const float* ebhh = (const float*)d_in[5];
    const float* dWih = (const float*)d_in[6];
    const float* dWhh = (const float*)d_in[7];
    const float* dbih = (const float*)d_in[8];
    const float* dbhh = (const float*)d_in[9];
    const float* linW = (const float*)d_in[10];
    const float* linb = (const float*)d_in[11];
    const float* emb  = (const float*)d_in[12];
    float* out = (float*)d_out;

    hipMemsetAsync(d_out, 0, (size_t)out_size * sizeof(float), stream);

    dim3 grid(BN_ / R_, 10);   // 325 x 10 blocks
    krnn_kernel<<<grid, dim3(256), 0, stream>>>(
        X, eWih, eWhh, ebih, ebhh, dWih, dWhh, dbih, dbhh, linW, linb, emb, out);
}